// Round 7
// baseline (262.361 us; speedup 1.0000x reference)
//
#include <hip/hip_runtime.h>
#include <math.h>

namespace {
__constant__ float kBaseAp[13] = {-31593.7f, 0.106747f, 24606.4f, -78561.9f, 13317.9f,
                                  307387.0f, 84916.1f, -1074690.0f, 2285.04f, 990894.0f,
                                  283920.0f, -161513.0f, -469218.0f};

constexpr double dTO  = 6.08671;
constexpr double dTSN = 1001.38;
constexpr double dTSP = 46.4311;
constexpr double dLAM = 58.0 / 63.0;          // 1 - (1/126 + 1/14)
constexpr double dAO  = 1.0 - 1.0 / dTO;
constexpr double dAN  = 1.0 - 1.0 / dTSN;
constexpr double dAP  = 1.0 - 1.0 / dTSP;

constexpr double cpow(double x, int n) {
    double r = 1.0;
    for (int i = 0; i < n; ++i) r *= x;
    return r;
}
}  // namespace

// asinh(z) = log(z + sqrt(z*z + 1)) — serial fallback only
__device__ __forceinline__ float fast_asinh(float z) {
    return __logf(z + sqrtf(__fmaf_rn(z, z, 1.0f)));
}

// ============================================================================
// Wave-parallel scan kernel: one 64-lane wave per batch element, 16 steps/lane.
// Valid for T <= 1024.
//
// Exact linear decomposition (R2-R6, verified passing):
//   QN'=QN-i (prefix sum); d'=lam*d +- i/14 (lam=58/63); x=(Q-+S)*cA - cB*d;
//   Vo,Vsn,Vsp geometric IIRs -> wave scans + per-lane replay.
// R5/R6: per-segment linearization at the 16-step anchor (error <~2e-4 V).
//
// R7: register diet for 8 waves/SIMD. The IIR drives vn=(i*kn)*w(i^2*gn2),
// vp=i*kp depend ONLY on i and anchor constants -> no nsn/nsp/epn arrays:
//   pass A: accumulate IIR segment sums (c_o,c_sn,c_sp) — ~11 ops/step
//   pass B (after scans): recompute drives, replay IIRs + dx evolution,
//           emit outputs through a 4-float staging buffer — ~24 ops/step
// Only cur[16] stays in registers. __launch_bounds__(256,8) caps VGPR at 64.
// ============================================================================
__global__ __launch_bounds__(256, 8) void battery_scan_kernel(
    const float* __restrict__ current,     // [B,T]
    const float* __restrict__ init_state,  // [B,8]
    const float* __restrict__ Ap_scale,    // [13]
    const float* __restrict__ An0_scale,   // [1]
    float* __restrict__ out,               // [B,T]
    int B, int T)
{
    constexpr int L = 16;                       // timesteps per lane
    const int lane = threadIdx.x & 63;
    const int wid  = threadIdx.x >> 6;
    const int b    = blockIdx.x * (blockDim.x >> 6) + wid;
    if (b >= B) return;                         // wave-uniform

    // ---- constants ----
    const float invF   = (float)(1.0 / 96487.0);
    const float invQS  = (float)(1.0 / (7600.0 / 0.6 * 0.1));
    const float inv14  = (float)(1.0 / 14.0);
    const float lam    = (float)dLAM;
    const float lm1    = (float)(dLAM - 1.0);
    const float ao     = (float)dAO, an = (float)dAN, ap = (float)dAP;
    const float c1n = (float)(1.0 / (0.000437545 * 2.0 * 2120.96));
    const float c1p = (float)(1.0 / (0.00030962 * 2.0 * 248898.0));
    const float cA  = 0.1f * invQS;
    const float cB  = 12.6f * invQS;
    const float cRO    = (float)(0.117215 / dTO);
    const float invcRO = (float)(dTO / 0.117215);
    const float CC  = 4.03f - 0.01f;            // U0P - U0N
    // asinh(z)/z = 1 + z2*(a1 + z2*(a2 + z2*a3)), |z|<=0.56
    const float a1 = -1.0f / 6.0f, a2 = 3.0f / 40.0f, a3 = -15.0f / 336.0f;

    // scan level constants pole^(16*2^k), k=0..5 (compile-time literals)
    const float lamL[6] = {(float)cpow(dLAM,16),(float)cpow(dLAM,32),(float)cpow(dLAM,64),
                           (float)cpow(dLAM,128),(float)cpow(dLAM,256),(float)cpow(dLAM,512)};
    const float aoL[6]  = {(float)cpow(dAO,16),(float)cpow(dAO,32),(float)cpow(dAO,64),
                           (float)cpow(dAO,128),(float)cpow(dAO,256),(float)cpow(dAO,512)};
    const float anL[6]  = {(float)cpow(dAN,16),(float)cpow(dAN,32),(float)cpow(dAN,64),
                           (float)cpow(dAN,128),(float)cpow(dAN,256),(float)cpow(dAN,512)};
    const float apL[6]  = {(float)cpow(dAP,16),(float)cpow(dAP,32),(float)cpow(dAP,64),
                           (float)cpow(dAP,128),(float)cpow(dAP,256),(float)cpow(dAP,512)};

    // per-lane anchors pole^(16*lane): binary exponentiation over lane bits
    float lamt = 1.0f, aot = 1.0f, ant = 1.0f, apt = 1.0f;
    #pragma unroll
    for (int k = 0; k < 6; ++k) {
        if (lane & (1 << k)) {
            lamt *= lamL[k];
            aot  *= aoL[k];
            ant  *= anL[k];
            apt  *= apL[k];
        }
    }

    // ---- per-element init state ----
    const float* st = init_state + (size_t)b * 8;
    const float Tb = st[0], Vo0 = st[1], Vsn0 = st[2], Vsp0 = st[3];
    const float qnB0 = st[4], qnS0 = st[5], qpB0 = st[6], qpS0 = st[7];
    const float QN0 = qnB0 + qnS0;
    const float QP0 = qpB0 + qpS0;
    const float dn0 = qnB0 * (float)(1.0/126.0) - qnS0 * inv14;
    const float dp0 = qpB0 * (float)(1.0/126.0) - qpS0 * inv14;
    const float coefVs = 8.3144621f * Tb * invF * 2.0f;
    const float coefL  = 8.3144621f * Tb * invF;
    const float cVn = coefVs * (float)(1.0 / dTSN);
    const float cVp = coefVs * (float)(1.0 / dTSP);

    // ---- load this lane's 16 currents (float4, tail-guarded) ----
    const float* row = current + (size_t)b * T;
    const int t0 = lane * L;
    float cur[L];
    #pragma unroll
    for (int k = 0; k < L / 4; ++k) {
        const int t = t0 + 4 * k;
        if (t + 4 <= T) {
            const float4 v = *reinterpret_cast<const float4*>(row + t);
            cur[4*k+0] = v.x; cur[4*k+1] = v.y; cur[4*k+2] = v.z; cur[4*k+3] = v.w;
        } else {
            #pragma unroll
            for (int m = 0; m < 4; ++m)
                cur[4*k+m] = (t + m < T) ? row[t + m] : 0.0f;
        }
    }

    // ---- phase 1: local reductions for S (cumsum) and h (d' = lam*d + i/14) ----
    float s_loc = 0.0f, cH = 0.0f;
    #pragma unroll
    for (int j = 0; j < L; ++j) {
        s_loc += cur[j];
        cH = __fmaf_rn(lam, cH, cur[j] * inv14);
    }

    // ---- phase 2: cumsum scan + C-only affine scan for h ----
    float s = s_loc;
    #pragma unroll
    for (int d = 1; d < 64; d <<= 1) {
        const float o = __shfl_up(s, (unsigned)d, 64);
        if (lane >= d) s += o;
    }
    const float Sx = s - s_loc;          // exclusive prefix sum at segment start

    float Ch = cH;
    #pragma unroll
    for (int k = 0; k < 6; ++k) {
        const int d = 1 << k;
        const float o = __shfl_up(Ch, (unsigned)d, 64);
        if (lane >= d) Ch = __fmaf_rn(lamL[k], o, Ch);
    }
    float h = __shfl_up(Ch, 1u, 64);
    if (lane == 0) h = 0.0f;

    // ---- anchor state at t0 ----
    float dn = __fmaf_rn(lamt, dn0, h);
    float dp = __fmaf_rn(lamt, dp0, -h);
    const float xn0 = (QN0 - Sx) * cA - dn * cB;
    const float xp0 = (QP0 + Sx) * cA - dp * cB;

    // ---- per-segment heavy eval (once per wave); RK coeffs scoped here ----
    float K0, Kn, Kp, gn2, kn, kp;
    {
        const float pn0 = __fmaf_rn(-xn0, xn0, xn0);      // xn0*(1-xn0)
        const float pp0 = __fmaf_rn(-xp0, xp0, xp0);
        const float rn = __frsqrt_rn(pn0), rp = __frsqrt_rn(pp0);
        const float rn2 = rn * rn, rp2 = rp * rp;         // 1/(x(1-x))
        const float gn = c1n * rn;
        gn2 = gn * gn;
        kn  = cVn * gn;
        kp  = (cVp * c1p) * rp;
        const float fxn = __logf(__fdividef(1.0f - xn0, xn0));
        const float fxp = __logf(__fdividef(1.0f - xp0, xp0));

        float alpha[13], beta[13];
        #pragma unroll
        for (int k = 0; k < 13; ++k) {
            const float A = Ap_scale[k] * kBaseAp[k] * invF;
            alpha[k] = A * (1.0f + 0.5f * (float)k);
            beta[k]  = -A * (0.5f * (float)k);
        }
        const float e0 = beta[1];
        const float e1 = alpha[1] + beta[3];
        const float e2 = alpha[3] + beta[5];
        const float e3 = alpha[5] + beta[7];
        const float e4 = alpha[7] + beta[9];
        const float e5 = alpha[9] + beta[11];
        const float e6 = alpha[11];
        const float o0 = (Ap_scale[0] * kBaseAp[0] * invF) + beta[2];
        const float o1 = alpha[2]  + beta[4];
        const float o2 = alpha[4]  + beta[6];
        const float o3 = alpha[6]  + beta[8];
        const float o4 = alpha[8]  + beta[10];
        const float o5 = alpha[10] + beta[12];
        const float o6 = alpha[12];

        const float tp0 = 2.0f * xp0 - 1.0f;
        const float u0  = tp0 * tp0;
        float E = __fmaf_rn(e6, u0, e5);
        E = __fmaf_rn(E, u0, e4); E = __fmaf_rn(E, u0, e3);
        E = __fmaf_rn(E, u0, e2); E = __fmaf_rn(E, u0, e1); E = __fmaf_rn(E, u0, e0);
        float O = __fmaf_rn(o6, u0, o5);
        O = __fmaf_rn(O, u0, o4); O = __fmaf_rn(O, u0, o3);
        O = __fmaf_rn(O, u0, o2); O = __fmaf_rn(O, u0, o1); O = __fmaf_rn(O, u0, o0);
        float Ep = __fmaf_rn(6.0f*e6, u0, 5.0f*e5);
        Ep = __fmaf_rn(Ep, u0, 4.0f*e4); Ep = __fmaf_rn(Ep, u0, 3.0f*e3);
        Ep = __fmaf_rn(Ep, u0, 2.0f*e2); Ep = __fmaf_rn(Ep, u0, e1);
        float Op = __fmaf_rn(6.0f*o6, u0, 5.0f*o5);
        Op = __fmaf_rn(Op, u0, 4.0f*o4); Op = __fmaf_rn(Op, u0, 3.0f*o3);
        Op = __fmaf_rn(Op, u0, 2.0f*o2); Op = __fmaf_rn(Op, u0, o1);
        const float rkf0 = __fmaf_rn(tp0, O, E);          // RK/F at anchor
        float Fp = __fmaf_rn(2.0f * tp0, Ep, O);          // dRK/dt = 2t E' + O + 2u O'
        Fp = __fmaf_rn(2.0f * u0, Op, Fp);

        const float AnF = An0_scale[0] * 86.19f * invF;
        const float tn0 = 2.0f * xn0 - 1.0f;
        K0 = CC + coefL * (fxp - fxn) + rkf0 - AnF * tn0;
        Kn = __fmaf_rn(coefL, rn2, -2.0f * AnF);          // -dVen/dxn
        Kp = __fmaf_rn(-coefL, rp2, 2.0f * Fp);           // dVep/dxp
    }

    // ---- pass A: IIR segment sums (drives depend only on i + anchor consts) ----
    float c_o = 0.0f, c_sn = 0.0f, c_sp = 0.0f;
    #pragma unroll
    for (int j = 0; j < L; ++j) {
        const float i = cur[j];
        const float z2 = (i * i) * gn2;
        float Q = __fmaf_rn(a3, z2, a2);
        Q = __fmaf_rn(Q, z2, a1);
        const float vn = (i * kn) * __fmaf_rn(z2, Q, 1.0f);
        c_sn = __fmaf_rn(an, c_sn, vn);
        c_sp = __fmaf_rn(ap, c_sp, i * kp);
        c_o  = __fmaf_rn(ao, c_o, i);
    }

    // ---- phase 4: three C-only IIR scans ----
    float Co = c_o, Cn = c_sn, Cp = c_sp;
    #pragma unroll
    for (int k = 0; k < 6; ++k) {
        const int d = 1 << k;
        const float oo = __shfl_up(Co, (unsigned)d, 64);
        const float on = __shfl_up(Cn, (unsigned)d, 64);
        const float op = __shfl_up(Cp, (unsigned)d, 64);
        if (lane >= d) {
            Co = __fmaf_rn(aoL[k], oo, Co);
            Cn = __fmaf_rn(anL[k], on, Cn);
            Cp = __fmaf_rn(apL[k], op, Cp);
        }
    }
    float Cxo = __shfl_up(Co, 1u, 64);
    float Cxn = __shfl_up(Cn, 1u, 64);
    float Cxp = __shfl_up(Cp, 1u, 64);
    if (lane == 0) { Cxo = 0.0f; Cxn = 0.0f; Cxp = 0.0f; }
    float vo  = __fmaf_rn(aot, Vo0 * invcRO, Cxo);   // Vo/cRO at segment start
    float vsn = __fmaf_rn(ant, Vsn0, Cxn);
    float vsp = __fmaf_rn(apt, Vsp0, Cxp);

    // ---- pass B: replay — recompute drives, evolve dx, emit outputs ----
    float* orow = out + (size_t)b * T;
    float dxn = 0.0f, dxp = 0.0f;
    float buf[4];
    #pragma unroll
    for (int j = 0; j < L; ++j) {
        const float i = cur[j];
        // drives (identical formula to pass A)
        const float z2 = (i * i) * gn2;
        float Q = __fmaf_rn(a3, z2, a2);
        Q = __fmaf_rn(Q, z2, a1);
        const float vn = (i * kn) * __fmaf_rn(z2, Q, 1.0f);
        vo  = __fmaf_rn(ao, vo, i);
        vsn = __fmaf_rn(an, vsn, vn);
        vsp = __fmaf_rn(ap, vsp, i * kp);
        // linear state advance to t+1
        const float t14 = i * inv14;
        const float ddn = __fmaf_rn(lm1, dn, t14);
        const float ddp = __fmaf_rn(lm1, dp, -t14);
        dn += ddn; dp += ddp;
        dxn = __fmaf_rn(-cB, ddn, dxn); dxn = __fmaf_rn(-cA, i, dxn);
        dxp = __fmaf_rn(-cB, ddp, dxp); dxp = __fmaf_rn( cA, i, dxp);
        // linearized potential at t+1, minus IIR voltages
        const float ep = __fmaf_rn(Kn, dxn, __fmaf_rn(Kp, dxp, K0));
        buf[j & 3] = (ep - vsn - vsp) - cRO * vo;
        if ((j & 3) == 3) {
            const int t = t0 + j - 3;
            if (t + 4 <= T) {
                *reinterpret_cast<float4*>(orow + t) =
                    make_float4(buf[0], buf[1], buf[2], buf[3]);
            } else {
                #pragma unroll
                for (int m = 0; m < 4; ++m)
                    if (t + m < T) orow[t + m] = buf[m];
            }
        }
    }
}

// ============================================================================
// Serial fallback for T > 1024 — correctness insurance only.
// ============================================================================
__global__ __launch_bounds__(64) void battery_serial_kernel(
    const float* __restrict__ current, const float* __restrict__ init_state,
    const float* __restrict__ Ap_scale, const float* __restrict__ An0_scale,
    float* __restrict__ out, int B, int T)
{
    const int b = blockIdx.x * blockDim.x + threadIdx.x;
    if (b >= B) return;

    const float invF = (float)(1.0 / 96487.0);
    const float RO = 0.117215f, KN = 2120.96f, KP = 248898.0f;
    const float invQS = (float)(1.0 / (7600.0 / 0.6 * 0.1));
    const float iVB = (float)(1.0 / 126.0), iVS = (float)(1.0 / 14.0);
    const float invSN = (float)(1.0 / 0.000437545), invSP = (float)(1.0 / 0.00030962);
    const float invTO = (float)(1.0 / dTO), invTSN = (float)(1.0 / dTSN), invTSP = (float)(1.0 / dTSP);
    const float U0P = 4.03f, U0N = 0.01f;

    float Ap[13], Apk[13];
    #pragma unroll
    for (int k = 0; k < 13; ++k) { Ap[k] = Ap_scale[k] * kBaseAp[k]; Apk[k] = Ap[k] * (float)k; }
    const float An0 = An0_scale[0] * 86.19f;

    const float* st = init_state + (size_t)b * 8;
    float Tb = st[0], Vo = st[1], Vsn = st[2], Vsp = st[3];
    float qnB = st[4], qnS = st[5], qpB = st[6], qpS = st[7];
    const float coefVs = 8.3144621f * Tb * invF * 2.0f;
    const float coefL  = 8.3144621f * Tb * invF;

    const float* cur = current + (size_t)b * T;
    float* op = out + (size_t)b * T;

    for (int t = 0; t < T; ++t) {
        const float i = cur[t];
        float xnS = qnS * invQS, xpS = qpS * invQS;
        float Jn0 = KN * sqrtf(xnS * (1.0f - xnS));
        float Jp0 = KP * sqrtf(xpS * (1.0f - xpS));
        float dBSn = qnB * iVB - qnS * iVS;
        float dBSp = qpB * iVB - qpS * iVS;
        float zn = __fdividef(i * invSN, 2.0f * Jn0);
        float zp = __fdividef(i * invSP, 2.0f * Jp0);
        Vo  += (i * RO - Vo) * invTO;
        Vsn += (coefVs * fast_asinh(zn) - Vsn) * invTSN;
        Vsp += (coefVs * fast_asinh(zp) - Vsp) * invTSP;
        qnB -= dBSn; qnS += dBSn - i; qpB -= dBSp; qpS += i + dBSp;

        float xp = qpS * invQS, xn = qnS * invQS;
        float lp = __logf(__fdividef(1.0f - xp, xp));
        float ln = __logf(__fdividef(1.0f - xn, xn));
        float tp = 2.0f * xp - 1.0f, cp2 = 2.0f * xp * (1.0f - xp);
        float sum = Ap[0] * tp, pkm1 = 1.0f, pk = tp;
        #pragma unroll
        for (int k = 1; k < 13; ++k) {
            float pk1 = pk * tp;
            sum = __fmaf_rn(Ap[k], pk1, sum);
            sum = __fmaf_rn(-Apk[k] * cp2, pkm1, sum);
            pkm1 = pk; pk = pk1;
        }
        float tn = 2.0f * xn - 1.0f;
        op[t] = (U0P - U0N) + coefL * (lp - ln) + (sum - An0 * tn) * invF - Vo - Vsn - Vsp;
    }
}

extern "C" void kernel_launch(void* const* d_in, const int* in_sizes, int n_in,
                              void* d_out, int out_size, void* d_ws, size_t ws_size,
                              hipStream_t stream) {
    const float* current    = (const float*)d_in[0];
    const float* init_state = (const float*)d_in[1];
    const float* Ap_scale   = (const float*)d_in[2];
    const float* An0_scale  = (const float*)d_in[3];
    float* out = (float*)d_out;

    const int B = in_sizes[1] / 8;   // init_state is [B,8]
    const int T = in_sizes[0] / B;   // current is [B,T]

    if (T <= 1024) {
        // one 64-lane wave per batch element, 4 waves per 256-thread block
        dim3 block(256);
        dim3 grid((B + 3) / 4);
        hipLaunchKernelGGL(battery_scan_kernel, grid, block, 0, stream,
                           current, init_state, Ap_scale, An0_scale, out, B, T);
    } else {
        dim3 block(64);
        dim3 grid((B + 63) / 64);
        hipLaunchKernelGGL(battery_serial_kernel, grid, block, 0, stream,
                           current, init_state, Ap_scale, An0_scale, out, B, T);
    }
}

// Round 8
// 130.501 us; speedup vs baseline: 2.0104x; 2.0104x over previous
//
#include <hip/hip_runtime.h>
#include <math.h>

namespace {
__constant__ float kBaseAp[13] = {-31593.7f, 0.106747f, 24606.4f, -78561.9f, 13317.9f,
                                  307387.0f, 84916.1f, -1074690.0f, 2285.04f, 990894.0f,
                                  283920.0f, -161513.0f, -469218.0f};

constexpr double dTO  = 6.08671;
constexpr double dTSN = 1001.38;
constexpr double dTSP = 46.4311;
constexpr double dLAM = 58.0 / 63.0;          // 1 - (1/126 + 1/14)
constexpr double dAO  = 1.0 - 1.0 / dTO;
constexpr double dAN  = 1.0 - 1.0 / dTSN;
constexpr double dAP  = 1.0 - 1.0 / dTSP;

constexpr double cpow(double x, int n) {
    double r = 1.0;
    for (int i = 0; i < n; ++i) r *= x;
    return r;
}
}  // namespace

// force a (wave-uniform) float into an SGPR
__device__ __forceinline__ float rfl(float x) {
    union { float f; int i; } u;
    u.f = x;
    u.i = __builtin_amdgcn_readfirstlane(u.i);
    return u.f;
}

// asinh(z) = log(z + sqrt(z*z + 1)) — serial fallback only
__device__ __forceinline__ float fast_asinh(float z) {
    return __logf(z + sqrtf(__fmaf_rn(z, z, 1.0f)));
}

// ============================================================================
// Wave-parallel scan kernel: one 64-lane wave per batch element, 16 steps/lane.
// Valid for T <= 1024.
//
// Exact linear decomposition (R2-R7, verified passing):
//   QN'=QN-i (prefix sum); d'=lam*d +- i/14 (lam=58/63); x=(Q-+S)*cA - cB*d;
//   Vo,Vsn,Vsp geometric IIRs -> wave scans + per-lane replay.
// R5/R6: per-segment linearization at the 16-step anchor (error <~2e-4 V).
//
// R8: register diet WITHOUT a forced cap (R7's (256,8) cap caused scratch
// spills: VGPR 32, 600 MB scratch traffic, 6x regression). Here:
//   * no cur[16] array — currents reloaded from global per pass (L2-resident)
//   * uniform RK coefficients pushed to SGPRs via readfirstlane
//   * pass-B emits ep = K0' - KnB*dn - KpB*dp + KdA*dS (3 fma, minimal state)
//   * c_o / c_sp-raw weighted sums folded into phase 1 (vp = kp*i factors out)
//   * __launch_bounds__(256,6): cap ~85 >> expected ~55-65 natural demand;
//     runtime occupancy follows actual allocation (<=64 -> 8 waves/SIMD).
// ============================================================================
__global__ __launch_bounds__(256, 6) void battery_scan_kernel(
    const float* __restrict__ current,     // [B,T]
    const float* __restrict__ init_state,  // [B,8]
    const float* __restrict__ Ap_scale,    // [13]
    const float* __restrict__ An0_scale,   // [1]
    float* __restrict__ out,               // [B,T]
    int B, int T)
{
    constexpr int L = 16;                       // timesteps per lane
    const int lane = threadIdx.x & 63;
    const int wid  = threadIdx.x >> 6;
    const int b    = blockIdx.x * (blockDim.x >> 6) + wid;
    if (b >= B) return;                         // wave-uniform

    // ---- constants ----
    const float invF   = (float)(1.0 / 96487.0);
    const float invQS  = (float)(1.0 / (7600.0 / 0.6 * 0.1));
    const float inv14  = (float)(1.0 / 14.0);
    const float lam    = (float)dLAM;
    const float ao     = (float)dAO, an = (float)dAN, ap = (float)dAP;
    const float c1n = (float)(1.0 / (0.000437545 * 2.0 * 2120.96));
    const float c1p = (float)(1.0 / (0.00030962 * 2.0 * 248898.0));
    const float cA  = 0.1f * invQS;
    const float cB  = 12.6f * invQS;
    const float cRO    = (float)(0.117215 / dTO);
    const float invcRO = (float)(dTO / 0.117215);
    const float CC  = 4.03f - 0.01f;            // U0P - U0N
    // asinh(z)/z = 1 + z2*(a1 + z2*(a2 + z2*a3)), |z|<=0.56
    const float a1 = -1.0f / 6.0f, a2 = 3.0f / 40.0f, a3 = -15.0f / 336.0f;

    // scan level constants pole^(16*2^k), k=0..5 (compile-time literals)
    const float lamL[6] = {(float)cpow(dLAM,16),(float)cpow(dLAM,32),(float)cpow(dLAM,64),
                           (float)cpow(dLAM,128),(float)cpow(dLAM,256),(float)cpow(dLAM,512)};
    const float aoL[6]  = {(float)cpow(dAO,16),(float)cpow(dAO,32),(float)cpow(dAO,64),
                           (float)cpow(dAO,128),(float)cpow(dAO,256),(float)cpow(dAO,512)};
    const float anL[6]  = {(float)cpow(dAN,16),(float)cpow(dAN,32),(float)cpow(dAN,64),
                           (float)cpow(dAN,128),(float)cpow(dAN,256),(float)cpow(dAN,512)};
    const float apL[6]  = {(float)cpow(dAP,16),(float)cpow(dAP,32),(float)cpow(dAP,64),
                           (float)cpow(dAP,128),(float)cpow(dAP,256),(float)cpow(dAP,512)};

    // per-lane anchors pole^(16*lane): binary exponentiation over lane bits
    float lamt = 1.0f, aot = 1.0f, ant = 1.0f, apt = 1.0f;
    #pragma unroll
    for (int k = 0; k < 6; ++k) {
        if (lane & (1 << k)) {
            lamt *= lamL[k];
            aot  *= aoL[k];
            ant  *= anL[k];
            apt  *= apL[k];
        }
    }

    // ---- grid-uniform RK E/O Horner coefficients -> SGPRs (invF folded) ----
    float e0,e1,e2,e3,e4,e5,e6, o0,o1,o2,o3,o4,o5,o6, AnF;
    {
        float al[13], be[13];
        #pragma unroll
        for (int k = 0; k < 13; ++k) {
            const float A = Ap_scale[k] * kBaseAp[k] * invF;
            al[k] = A * (1.0f + 0.5f * (float)k);
            be[k] = -A * (0.5f * (float)k);
        }
        e0 = rfl(be[1]);
        e1 = rfl(al[1] + be[3]);
        e2 = rfl(al[3] + be[5]);
        e3 = rfl(al[5] + be[7]);
        e4 = rfl(al[7] + be[9]);
        e5 = rfl(al[9] + be[11]);
        e6 = rfl(al[11]);
        o0 = rfl((Ap_scale[0] * kBaseAp[0] * invF) + be[2]);
        o1 = rfl(al[2]  + be[4]);
        o2 = rfl(al[4]  + be[6]);
        o3 = rfl(al[6]  + be[8]);
        o4 = rfl(al[8]  + be[10]);
        o5 = rfl(al[10] + be[12]);
        o6 = rfl(al[12]);
        AnF = rfl(An0_scale[0] * 86.19f * invF);
    }

    // ---- per-element init state ----
    const float* st = init_state + (size_t)b * 8;
    const float Tb = st[0], Vo0 = st[1], Vsn0 = st[2], Vsp0 = st[3];
    const float qnB0 = st[4], qnS0 = st[5], qpB0 = st[6], qpS0 = st[7];
    const float QN0 = qnB0 + qnS0;
    const float QP0 = qpB0 + qpS0;
    const float dn0 = qnB0 * (float)(1.0/126.0) - qnS0 * inv14;
    const float dp0 = qpB0 * (float)(1.0/126.0) - qpS0 * inv14;
    const float coefVs = 8.3144621f * Tb * invF * 2.0f;
    const float coefL  = 8.3144621f * Tb * invF;
    const float cVn = coefVs * (float)(1.0 / dTSN);
    const float cVp = coefVs * (float)(1.0 / dTSP);

    const float* row  = current + (size_t)b * T;
    float* orow = out + (size_t)b * T;
    const int t0 = lane * L;

    // ---- phase 1: weighted local reductions from the quad loads ----
    // s_loc (plain), cH (lam-weighted * 1/14), c_o (ao-weighted i),
    // c_spr (ap-weighted i; drive vp = kp*i so kp factors out of the scan input)
    float s_loc = 0.0f, cH = 0.0f, c_o = 0.0f, c_spr = 0.0f;
    #pragma unroll
    for (int k4 = 0; k4 < 4; ++k4) {
        const int t = t0 + 4 * k4;
        float4 v;
        if (t + 4 <= T) {
            v = *reinterpret_cast<const float4*>(row + t);
        } else {
            v.x = (t     < T) ? row[t]     : 0.0f;
            v.y = (t + 1 < T) ? row[t + 1] : 0.0f;
            v.z = (t + 2 < T) ? row[t + 2] : 0.0f;
            v.w = (t + 3 < T) ? row[t + 3] : 0.0f;
        }
        const float q[4] = {v.x, v.y, v.z, v.w};
        #pragma unroll
        for (int m = 0; m < 4; ++m) {
            const float i = q[m];
            s_loc += i;
            cH    = __fmaf_rn(lam, cH, i * inv14);
            c_o   = __fmaf_rn(ao, c_o, i);
            c_spr = __fmaf_rn(ap, c_spr, i);
        }
    }

    // ---- phase 2: cumsum scan + C-only affine scan for h ----
    float s = s_loc;
    #pragma unroll
    for (int d = 1; d < 64; d <<= 1) {
        const float o = __shfl_up(s, (unsigned)d, 64);
        if (lane >= d) s += o;
    }
    const float Sx = s - s_loc;          // exclusive prefix sum at segment start

    float Ch = cH;
    #pragma unroll
    for (int k = 0; k < 6; ++k) {
        const int d = 1 << k;
        const float o = __shfl_up(Ch, (unsigned)d, 64);
        if (lane >= d) Ch = __fmaf_rn(lamL[k], o, Ch);
    }
    float h = __shfl_up(Ch, 1u, 64);
    if (lane == 0) h = 0.0f;

    // ---- anchor state at t0 ----
    float dn = __fmaf_rn(lamt, dn0, h);
    float dp = __fmaf_rn(lamt, dp0, -h);
    const float xn0 = (QN0 - Sx) * cA - dn * cB;
    const float xp0 = (QP0 + Sx) * cA - dp * cB;

    // ---- per-segment heavy eval (once per wave) ----
    float K0p, KnB, KpB, KdA, gn2, kn, kp;
    {
        const float pn0 = __fmaf_rn(-xn0, xn0, xn0);      // xn0*(1-xn0)
        const float pp0 = __fmaf_rn(-xp0, xp0, xp0);
        const float rn = __frsqrt_rn(pn0), rp = __frsqrt_rn(pp0);
        const float rn2 = rn * rn, rp2 = rp * rp;         // 1/(x(1-x))
        const float gn = c1n * rn;
        gn2 = gn * gn;
        kn  = cVn * gn;
        kp  = (cVp * c1p) * rp;
        const float fxn = __logf(__fdividef(1.0f - xn0, xn0));
        const float fxp = __logf(__fdividef(1.0f - xp0, xp0));

        const float tp0 = 2.0f * xp0 - 1.0f;
        const float u0  = tp0 * tp0;
        float E = __fmaf_rn(e6, u0, e5);
        E = __fmaf_rn(E, u0, e4); E = __fmaf_rn(E, u0, e3);
        E = __fmaf_rn(E, u0, e2); E = __fmaf_rn(E, u0, e1); E = __fmaf_rn(E, u0, e0);
        float O = __fmaf_rn(o6, u0, o5);
        O = __fmaf_rn(O, u0, o4); O = __fmaf_rn(O, u0, o3);
        O = __fmaf_rn(O, u0, o2); O = __fmaf_rn(O, u0, o1); O = __fmaf_rn(O, u0, o0);
        float Ep = __fmaf_rn(6.0f * e6, u0, 5.0f * e5);
        Ep = __fmaf_rn(Ep, u0, 4.0f * e4); Ep = __fmaf_rn(Ep, u0, 3.0f * e3);
        Ep = __fmaf_rn(Ep, u0, 2.0f * e2); Ep = __fmaf_rn(Ep, u0, e1);
        float Op = __fmaf_rn(6.0f * o6, u0, 5.0f * o5);
        Op = __fmaf_rn(Op, u0, 4.0f * o4); Op = __fmaf_rn(Op, u0, 3.0f * o3);
        Op = __fmaf_rn(Op, u0, 2.0f * o2); Op = __fmaf_rn(Op, u0, o1);
        const float rkf0 = __fmaf_rn(tp0, O, E);          // RK/F at anchor
        float Fp = __fmaf_rn(2.0f * tp0, Ep, O);          // dRK/dt = 2t E' + O + 2u O'
        Fp = __fmaf_rn(2.0f * u0, Op, Fp);

        const float tn0 = 2.0f * xn0 - 1.0f;
        const float K0 = CC + coefL * (fxp - fxn) + rkf0 - AnF * tn0;
        const float Kn = __fmaf_rn(coefL, rn2, -2.0f * AnF);   // -dVen/dxn
        const float Kp = __fmaf_rn(-coefL, rp2, 2.0f * Fp);    // dVep/dxp
        // ep_t = K0' - KnB*dn_t - KpB*dp_t + KdA*dS_t
        KnB = Kn * cB;
        KpB = Kp * cB;
        KdA = (Kp - Kn) * cA;
        K0p = K0 + KnB * dn + KpB * dp;   // dn,dp still hold anchor values here
    }

    // ---- pass A: nonlinear IIR segment sum c_sn (reload currents) ----
    float c_sn = 0.0f;
    #pragma unroll
    for (int k4 = 0; k4 < 4; ++k4) {
        const int t = t0 + 4 * k4;
        float4 v;
        if (t + 4 <= T) {
            v = *reinterpret_cast<const float4*>(row + t);
        } else {
            v.x = (t     < T) ? row[t]     : 0.0f;
            v.y = (t + 1 < T) ? row[t + 1] : 0.0f;
            v.z = (t + 2 < T) ? row[t + 2] : 0.0f;
            v.w = (t + 3 < T) ? row[t + 3] : 0.0f;
        }
        const float q[4] = {v.x, v.y, v.z, v.w};
        #pragma unroll
        for (int m = 0; m < 4; ++m) {
            const float i = q[m];
            const float z2 = (i * i) * gn2;
            float Q = __fmaf_rn(a3, z2, a2);
            Q = __fmaf_rn(Q, z2, a1);
            const float vn = (i * kn) * __fmaf_rn(z2, Q, 1.0f);
            c_sn = __fmaf_rn(an, c_sn, vn);
        }
    }
    const float c_sp = kp * c_spr;

    // ---- phase 4: three C-only IIR scans ----
    float Co = c_o, Cn = c_sn, Cp = c_sp;
    #pragma unroll
    for (int k = 0; k < 6; ++k) {
        const int d = 1 << k;
        const float oo = __shfl_up(Co, (unsigned)d, 64);
        const float on = __shfl_up(Cn, (unsigned)d, 64);
        const float op = __shfl_up(Cp, (unsigned)d, 64);
        if (lane >= d) {
            Co = __fmaf_rn(aoL[k], oo, Co);
            Cn = __fmaf_rn(anL[k], on, Cn);
            Cp = __fmaf_rn(apL[k], op, Cp);
        }
    }
    float Cxo = __shfl_up(Co, 1u, 64);
    float Cxn = __shfl_up(Cn, 1u, 64);
    float Cxp = __shfl_up(Cp, 1u, 64);
    if (lane == 0) { Cxo = 0.0f; Cxn = 0.0f; Cxp = 0.0f; }
    float vo  = __fmaf_rn(aot, Vo0 * invcRO, Cxo);   // Vo/cRO at segment start
    float vsn = __fmaf_rn(ant, Vsn0, Cxn);
    float vsp = __fmaf_rn(apt, Vsp0, Cxp);

    // ---- pass B: replay — recompute drives, evolve dn/dp/dS, emit outputs ----
    float dS = 0.0f;
    float buf[4];
    #pragma unroll
    for (int k4 = 0; k4 < 4; ++k4) {
        const int t = t0 + 4 * k4;
        float4 v;
        if (t + 4 <= T) {
            v = *reinterpret_cast<const float4*>(row + t);
        } else {
            v.x = (t     < T) ? row[t]     : 0.0f;
            v.y = (t + 1 < T) ? row[t + 1] : 0.0f;
            v.z = (t + 2 < T) ? row[t + 2] : 0.0f;
            v.w = (t + 3 < T) ? row[t + 3] : 0.0f;
        }
        const float q[4] = {v.x, v.y, v.z, v.w};
        #pragma unroll
        for (int m = 0; m < 4; ++m) {
            const float i = q[m];
            // drives (frozen-anchor forms, identical to pass A)
            const float z2 = (i * i) * gn2;
            float Q = __fmaf_rn(a3, z2, a2);
            Q = __fmaf_rn(Q, z2, a1);
            const float vn = (i * kn) * __fmaf_rn(z2, Q, 1.0f);
            vo  = __fmaf_rn(ao, vo, i);
            vsn = __fmaf_rn(an, vsn, vn);
            vsp = __fmaf_rn(ap, vsp, i * kp);
            // linear state advance to t+1
            const float t14 = i * inv14;
            dn = __fmaf_rn(lam, dn, t14);
            dp = __fmaf_rn(lam, dp, -t14);
            dS += i;
            // linearized potential at t+1, minus IIR voltages
            float ep = __fmaf_rn(KdA, dS, K0p);
            ep = __fmaf_rn(-KnB, dn, ep);
            ep = __fmaf_rn(-KpB, dp, ep);
            buf[m] = (ep - vsn - vsp) - cRO * vo;
        }
        if (t + 4 <= T) {
            *reinterpret_cast<float4*>(orow + t) =
                make_float4(buf[0], buf[1], buf[2], buf[3]);
        } else {
            #pragma unroll
            for (int m = 0; m < 4; ++m)
                if (t + m < T) orow[t + m] = buf[m];
        }
    }
}

// ============================================================================
// Serial fallback for T > 1024 — correctness insurance only.
// ============================================================================
__global__ __launch_bounds__(64) void battery_serial_kernel(
    const float* __restrict__ current, const float* __restrict__ init_state,
    const float* __restrict__ Ap_scale, const float* __restrict__ An0_scale,
    float* __restrict__ out, int B, int T)
{
    const int b = blockIdx.x * blockDim.x + threadIdx.x;
    if (b >= B) return;

    const float invF = (float)(1.0 / 96487.0);
    const float RO = 0.117215f, KN = 2120.96f, KP = 248898.0f;
    const float invQS = (float)(1.0 / (7600.0 / 0.6 * 0.1));
    const float iVB = (float)(1.0 / 126.0), iVS = (float)(1.0 / 14.0);
    const float invSN = (float)(1.0 / 0.000437545), invSP = (float)(1.0 / 0.00030962);
    const float invTO = (float)(1.0 / dTO), invTSN = (float)(1.0 / dTSN), invTSP = (float)(1.0 / dTSP);
    const float U0P = 4.03f, U0N = 0.01f;

    float Ap[13], Apk[13];
    #pragma unroll
    for (int k = 0; k < 13; ++k) { Ap[k] = Ap_scale[k] * kBaseAp[k]; Apk[k] = Ap[k] * (float)k; }
    const float An0 = An0_scale[0] * 86.19f;

    const float* st = init_state + (size_t)b * 8;
    float Tb = st[0], Vo = st[1], Vsn = st[2], Vsp = st[3];
    float qnB = st[4], qnS = st[5], qpB = st[6], qpS = st[7];
    const float coefVs = 8.3144621f * Tb * invF * 2.0f;
    const float coefL  = 8.3144621f * Tb * invF;

    const float* cur = current + (size_t)b * T;
    float* op = out + (size_t)b * T;

    for (int t = 0; t < T; ++t) {
        const float i = cur[t];
        float xnS = qnS * invQS, xpS = qpS * invQS;
        float Jn0 = KN * sqrtf(xnS * (1.0f - xnS));
        float Jp0 = KP * sqrtf(xpS * (1.0f - xpS));
        float dBSn = qnB * iVB - qnS * iVS;
        float dBSp = qpB * iVB - qpS * iVS;
        float zn = __fdividef(i * invSN, 2.0f * Jn0);
        float zp = __fdividef(i * invSP, 2.0f * Jp0);
        Vo  += (i * RO - Vo) * invTO;
        Vsn += (coefVs * fast_asinh(zn) - Vsn) * invTSN;
        Vsp += (coefVs * fast_asinh(zp) - Vsp) * invTSP;
        qnB -= dBSn; qnS += dBSn - i; qpB -= dBSp; qpS += i + dBSp;

        float xp = qpS * invQS, xn = qnS * invQS;
        float lp = __logf(__fdividef(1.0f - xp, xp));
        float ln = __logf(__fdividef(1.0f - xn, xn));
        float tp = 2.0f * xp - 1.0f, cp2 = 2.0f * xp * (1.0f - xp);
        float sum = Ap[0] * tp, pkm1 = 1.0f, pk = tp;
        #pragma unroll
        for (int k = 1; k < 13; ++k) {
            float pk1 = pk * tp;
            sum = __fmaf_rn(Ap[k], pk1, sum);
            sum = __fmaf_rn(-Apk[k] * cp2, pkm1, sum);
            pkm1 = pk; pk = pk1;
        }
        float tn = 2.0f * xn - 1.0f;
        op[t] = (U0P - U0N) + coefL * (lp - ln) + (sum - An0 * tn) * invF - Vo - Vsn - Vsp;
    }
}

extern "C" void kernel_launch(void* const* d_in, const int* in_sizes, int n_in,
                              void* d_out, int out_size, void* d_ws, size_t ws_size,
                              hipStream_t stream) {
    const float* current    = (const float*)d_in[0];
    const float* init_state = (const float*)d_in[1];
    const float* Ap_scale   = (const float*)d_in[2];
    const float* An0_scale  = (const float*)d_in[3];
    float* out = (float*)d_out;

    const int B = in_sizes[1] / 8;   // init_state is [B,8]
    const int T = in_sizes[0] / B;   // current is [B,T]

    if (T <= 1024) {
        // one 64-lane wave per batch element, 4 waves per 256-thread block
        dim3 block(256);
        dim3 grid((B + 3) / 4);
        hipLaunchKernelGGL(battery_scan_kernel, grid, block, 0, stream,
                           current, init_state, Ap_scale, An0_scale, out, B, T);
    } else {
        dim3 block(64);
        dim3 grid((B + 63) / 64);
        hipLaunchKernelGGL(battery_serial_kernel, grid, block, 0, stream,
                           current, init_state, Ap_scale, An0_scale, out, B, T);
    }
}

// Round 9
// 123.782 us; speedup vs baseline: 2.1195x; 1.0543x over previous
//
#include <hip/hip_runtime.h>
#include <math.h>

namespace {
__constant__ float kBaseAp[13] = {-31593.7f, 0.106747f, 24606.4f, -78561.9f, 13317.9f,
                                  307387.0f, 84916.1f, -1074690.0f, 2285.04f, 990894.0f,
                                  283920.0f, -161513.0f, -469218.0f};

constexpr double dTO  = 6.08671;
constexpr double dTSN = 1001.38;
constexpr double dTSP = 46.4311;
constexpr double dLAM = 58.0 / 63.0;          // 1 - (1/126 + 1/14)
constexpr double dAO  = 1.0 - 1.0 / dTO;
constexpr double dAN  = 1.0 - 1.0 / dTSN;
constexpr double dAP  = 1.0 - 1.0 / dTSP;

constexpr double cpow(double x, int n) {
    double r = 1.0;
    for (int i = 0; i < n; ++i) r *= x;
    return r;
}
}  // namespace

// force a (wave-uniform) float into an SGPR
__device__ __forceinline__ float rfl(float x) {
    union { float f; int i; } u;
    u.f = x;
    u.i = __builtin_amdgcn_readfirstlane(u.i);
    return u.f;
}

// asinh(z) = log(z + sqrt(z*z + 1)) — serial fallback only
__device__ __forceinline__ float fast_asinh(float z) {
    return __logf(z + sqrtf(__fmaf_rn(z, z, 1.0f)));
}

// ============================================================================
// Wave-parallel scan kernel: one 64-lane wave per batch element, 16 steps/lane.
// Valid for T <= 1024.
//
// Exact linear decomposition (R2-R8, verified passing):
//   QN'=QN-i (prefix sum); d'=lam*d +- i/14 (lam=58/63); x=(Q-+S)*cA - cB*d;
//   Vo,Vsn,Vsp geometric IIRs -> wave scans + per-lane replay.
// R5/R6: per-segment linearization at the 16-step anchor (error <~2e-4 V).
//
// R9 = R6's traffic profile + R8's register profile:
//   * cur[16] loaded ONCE (R8's global reloads missed L2 — 32MB input ==
//     entire aggregate L2 — and tripled HBM fetch: 89MB, 52us, memory-bound)
//   * no nsn/nsp/epn arrays (drives recomputed from cur in pass B)
//   * grid-uniform RK coefficients in SGPRs via readfirstlane (R7's VGPR
//     coefficient arrays under a hard (256,8) cap were what spilled)
//   * compact pass-B: ep = K0' - KnB*dn - KpB*dp + KdA*dS
//   * soft bound (256,6): natural demand ~56-64 -> 8 waves/SIMD w/o spill
// ============================================================================
__global__ __launch_bounds__(256, 6) void battery_scan_kernel(
    const float* __restrict__ current,     // [B,T]
    const float* __restrict__ init_state,  // [B,8]
    const float* __restrict__ Ap_scale,    // [13]
    const float* __restrict__ An0_scale,   // [1]
    float* __restrict__ out,               // [B,T]
    int B, int T)
{
    constexpr int L = 16;                       // timesteps per lane
    const int lane = threadIdx.x & 63;
    const int wid  = threadIdx.x >> 6;
    const int b    = blockIdx.x * (blockDim.x >> 6) + wid;
    if (b >= B) return;                         // wave-uniform

    // ---- constants ----
    const float invF   = (float)(1.0 / 96487.0);
    const float invQS  = (float)(1.0 / (7600.0 / 0.6 * 0.1));
    const float inv14  = (float)(1.0 / 14.0);
    const float lam    = (float)dLAM;
    const float ao     = (float)dAO, an = (float)dAN, ap = (float)dAP;
    const float c1n = (float)(1.0 / (0.000437545 * 2.0 * 2120.96));
    const float c1p = (float)(1.0 / (0.00030962 * 2.0 * 248898.0));
    const float cA  = 0.1f * invQS;
    const float cB  = 12.6f * invQS;
    const float cRO    = (float)(0.117215 / dTO);
    const float invcRO = (float)(dTO / 0.117215);
    const float CC  = 4.03f - 0.01f;            // U0P - U0N
    // asinh(z)/z = 1 + z2*(a1 + z2*(a2 + z2*a3)), |z|<=0.56
    const float a1 = -1.0f / 6.0f, a2 = 3.0f / 40.0f, a3 = -15.0f / 336.0f;

    // scan level constants pole^(16*2^k), k=0..5 (compile-time literals)
    const float lamL[6] = {(float)cpow(dLAM,16),(float)cpow(dLAM,32),(float)cpow(dLAM,64),
                           (float)cpow(dLAM,128),(float)cpow(dLAM,256),(float)cpow(dLAM,512)};
    const float aoL[6]  = {(float)cpow(dAO,16),(float)cpow(dAO,32),(float)cpow(dAO,64),
                           (float)cpow(dAO,128),(float)cpow(dAO,256),(float)cpow(dAO,512)};
    const float anL[6]  = {(float)cpow(dAN,16),(float)cpow(dAN,32),(float)cpow(dAN,64),
                           (float)cpow(dAN,128),(float)cpow(dAN,256),(float)cpow(dAN,512)};
    const float apL[6]  = {(float)cpow(dAP,16),(float)cpow(dAP,32),(float)cpow(dAP,64),
                           (float)cpow(dAP,128),(float)cpow(dAP,256),(float)cpow(dAP,512)};

    // per-lane anchors pole^(16*lane): binary exponentiation over lane bits
    float lamt = 1.0f, aot = 1.0f, ant = 1.0f, apt = 1.0f;
    #pragma unroll
    for (int k = 0; k < 6; ++k) {
        if (lane & (1 << k)) {
            lamt *= lamL[k];
            aot  *= aoL[k];
            ant  *= anL[k];
            apt  *= apL[k];
        }
    }

    // ---- grid-uniform RK E/O Horner coefficients -> SGPRs (invF folded) ----
    float e0,e1,e2,e3,e4,e5,e6, o0,o1,o2,o3,o4,o5,o6, AnF;
    {
        float al[13], be[13];
        #pragma unroll
        for (int k = 0; k < 13; ++k) {
            const float A = Ap_scale[k] * kBaseAp[k] * invF;
            al[k] = A * (1.0f + 0.5f * (float)k);
            be[k] = -A * (0.5f * (float)k);
        }
        e0 = rfl(be[1]);
        e1 = rfl(al[1] + be[3]);
        e2 = rfl(al[3] + be[5]);
        e3 = rfl(al[5] + be[7]);
        e4 = rfl(al[7] + be[9]);
        e5 = rfl(al[9] + be[11]);
        e6 = rfl(al[11]);
        o0 = rfl((Ap_scale[0] * kBaseAp[0] * invF) + be[2]);
        o1 = rfl(al[2]  + be[4]);
        o2 = rfl(al[4]  + be[6]);
        o3 = rfl(al[6]  + be[8]);
        o4 = rfl(al[8]  + be[10]);
        o5 = rfl(al[10] + be[12]);
        o6 = rfl(al[12]);
        AnF = rfl(An0_scale[0] * 86.19f * invF);
    }

    // ---- per-element init state ----
    const float* st = init_state + (size_t)b * 8;
    const float Tb = st[0], Vo0 = st[1], Vsn0 = st[2], Vsp0 = st[3];
    const float qnB0 = st[4], qnS0 = st[5], qpB0 = st[6], qpS0 = st[7];
    const float QN0 = qnB0 + qnS0;
    const float QP0 = qpB0 + qpS0;
    const float dn0 = qnB0 * (float)(1.0/126.0) - qnS0 * inv14;
    const float dp0 = qpB0 * (float)(1.0/126.0) - qpS0 * inv14;
    const float coefVs = 8.3144621f * Tb * invF * 2.0f;
    const float coefL  = 8.3144621f * Tb * invF;
    const float cVn = coefVs * (float)(1.0 / dTSN);
    const float cVp = coefVs * (float)(1.0 / dTSP);

    // ---- load this lane's 16 currents ONCE (float4, tail-guarded) ----
    const float* row = current + (size_t)b * T;
    const int t0 = lane * L;
    float cur[L];
    #pragma unroll
    for (int k = 0; k < L / 4; ++k) {
        const int t = t0 + 4 * k;
        if (t + 4 <= T) {
            const float4 v = *reinterpret_cast<const float4*>(row + t);
            cur[4*k+0] = v.x; cur[4*k+1] = v.y; cur[4*k+2] = v.z; cur[4*k+3] = v.w;
        } else {
            #pragma unroll
            for (int m = 0; m < 4; ++m)
                cur[4*k+m] = (t + m < T) ? row[t + m] : 0.0f;
        }
    }

    // ---- phase 1: weighted local reductions (everything linear in i) ----
    float s_loc = 0.0f, cH = 0.0f, c_o = 0.0f, c_spr = 0.0f;
    #pragma unroll
    for (int j = 0; j < L; ++j) {
        const float i = cur[j];
        s_loc += i;
        cH    = __fmaf_rn(lam, cH, i * inv14);
        c_o   = __fmaf_rn(ao, c_o, i);
        c_spr = __fmaf_rn(ap, c_spr, i);     // vp = kp*i -> kp folded in later
    }

    // ---- phase 2: cumsum scan + C-only affine scan for h ----
    float s = s_loc;
    #pragma unroll
    for (int d = 1; d < 64; d <<= 1) {
        const float o = __shfl_up(s, (unsigned)d, 64);
        if (lane >= d) s += o;
    }
    const float Sx = s - s_loc;          // exclusive prefix sum at segment start

    float Ch = cH;
    #pragma unroll
    for (int k = 0; k < 6; ++k) {
        const int d = 1 << k;
        const float o = __shfl_up(Ch, (unsigned)d, 64);
        if (lane >= d) Ch = __fmaf_rn(lamL[k], o, Ch);
    }
    float h = __shfl_up(Ch, 1u, 64);
    if (lane == 0) h = 0.0f;

    // ---- anchor state at t0 ----
    float dn = __fmaf_rn(lamt, dn0, h);
    float dp = __fmaf_rn(lamt, dp0, -h);
    const float xn0 = (QN0 - Sx) * cA - dn * cB;
    const float xp0 = (QP0 + Sx) * cA - dp * cB;

    // ---- per-segment heavy eval (once per wave) ----
    float K0p, KnB, KpB, KdA, gn2, kn, kp;
    {
        const float pn0 = __fmaf_rn(-xn0, xn0, xn0);      // xn0*(1-xn0)
        const float pp0 = __fmaf_rn(-xp0, xp0, xp0);
        const float rn = __frsqrt_rn(pn0), rp = __frsqrt_rn(pp0);
        const float rn2 = rn * rn, rp2 = rp * rp;         // 1/(x(1-x))
        const float gn = c1n * rn;
        gn2 = gn * gn;
        kn  = cVn * gn;
        kp  = (cVp * c1p) * rp;
        const float fxn = __logf(__fdividef(1.0f - xn0, xn0));
        const float fxp = __logf(__fdividef(1.0f - xp0, xp0));

        const float tp0 = 2.0f * xp0 - 1.0f;
        const float u0  = tp0 * tp0;
        float E = __fmaf_rn(e6, u0, e5);
        E = __fmaf_rn(E, u0, e4); E = __fmaf_rn(E, u0, e3);
        E = __fmaf_rn(E, u0, e2); E = __fmaf_rn(E, u0, e1); E = __fmaf_rn(E, u0, e0);
        float O = __fmaf_rn(o6, u0, o5);
        O = __fmaf_rn(O, u0, o4); O = __fmaf_rn(O, u0, o3);
        O = __fmaf_rn(O, u0, o2); O = __fmaf_rn(O, u0, o1); O = __fmaf_rn(O, u0, o0);
        float Ep = __fmaf_rn(6.0f * e6, u0, 5.0f * e5);
        Ep = __fmaf_rn(Ep, u0, 4.0f * e4); Ep = __fmaf_rn(Ep, u0, 3.0f * e3);
        Ep = __fmaf_rn(Ep, u0, 2.0f * e2); Ep = __fmaf_rn(Ep, u0, e1);
        float Op = __fmaf_rn(6.0f * o6, u0, 5.0f * o5);
        Op = __fmaf_rn(Op, u0, 4.0f * o4); Op = __fmaf_rn(Op, u0, 3.0f * o3);
        Op = __fmaf_rn(Op, u0, 2.0f * o2); Op = __fmaf_rn(Op, u0, o1);
        const float rkf0 = __fmaf_rn(tp0, O, E);          // RK/F at anchor
        float Fp = __fmaf_rn(2.0f * tp0, Ep, O);          // dRK/dt = 2t E' + O + 2u O'
        Fp = __fmaf_rn(2.0f * u0, Op, Fp);

        const float tn0 = 2.0f * xn0 - 1.0f;
        const float K0 = CC + coefL * (fxp - fxn) + rkf0 - AnF * tn0;
        const float Kn = __fmaf_rn(coefL, rn2, -2.0f * AnF);   // -dVen/dxn
        const float Kp = __fmaf_rn(-coefL, rp2, 2.0f * Fp);    // dVep/dxp
        // ep_t = K0' - KnB*dn_t - KpB*dp_t + KdA*dS_t
        KnB = Kn * cB;
        KpB = Kp * cB;
        KdA = (Kp - Kn) * cA;
        K0p = K0 + KnB * dn + KpB * dp;   // dn,dp still hold anchor values here
    }

    // ---- pass A: nonlinear IIR segment sum c_sn (from registers) ----
    float c_sn = 0.0f;
    #pragma unroll
    for (int j = 0; j < L; ++j) {
        const float i = cur[j];
        const float z2 = (i * i) * gn2;
        float Q = __fmaf_rn(a3, z2, a2);
        Q = __fmaf_rn(Q, z2, a1);
        const float vn = (i * kn) * __fmaf_rn(z2, Q, 1.0f);
        c_sn = __fmaf_rn(an, c_sn, vn);
    }
    const float c_sp = kp * c_spr;

    // ---- phase 4: three C-only IIR scans ----
    float Co = c_o, Cn = c_sn, Cp = c_sp;
    #pragma unroll
    for (int k = 0; k < 6; ++k) {
        const int d = 1 << k;
        const float oo = __shfl_up(Co, (unsigned)d, 64);
        const float on = __shfl_up(Cn, (unsigned)d, 64);
        const float op = __shfl_up(Cp, (unsigned)d, 64);
        if (lane >= d) {
            Co = __fmaf_rn(aoL[k], oo, Co);
            Cn = __fmaf_rn(anL[k], on, Cn);
            Cp = __fmaf_rn(apL[k], op, Cp);
        }
    }
    float Cxo = __shfl_up(Co, 1u, 64);
    float Cxn = __shfl_up(Cn, 1u, 64);
    float Cxp = __shfl_up(Cp, 1u, 64);
    if (lane == 0) { Cxo = 0.0f; Cxn = 0.0f; Cxp = 0.0f; }
    float vo  = __fmaf_rn(aot, Vo0 * invcRO, Cxo);   // Vo/cRO at segment start
    float vsn = __fmaf_rn(ant, Vsn0, Cxn);
    float vsp = __fmaf_rn(apt, Vsp0, Cxp);

    // ---- pass B: replay — recompute drives, evolve dn/dp/dS, emit outputs ----
    float* orow = out + (size_t)b * T;
    float dS = 0.0f;
    float buf[4];
    #pragma unroll
    for (int j = 0; j < L; ++j) {
        const float i = cur[j];
        // drives (frozen-anchor forms, identical to pass A)
        const float z2 = (i * i) * gn2;
        float Q = __fmaf_rn(a3, z2, a2);
        Q = __fmaf_rn(Q, z2, a1);
        const float vn = (i * kn) * __fmaf_rn(z2, Q, 1.0f);
        vo  = __fmaf_rn(ao, vo, i);
        vsn = __fmaf_rn(an, vsn, vn);
        vsp = __fmaf_rn(ap, vsp, i * kp);
        // linear state advance to t+1
        const float t14 = i * inv14;
        dn = __fmaf_rn(lam, dn, t14);
        dp = __fmaf_rn(lam, dp, -t14);
        dS += i;
        // linearized potential at t+1, minus IIR voltages
        float ep = __fmaf_rn(KdA, dS, K0p);
        ep = __fmaf_rn(-KnB, dn, ep);
        ep = __fmaf_rn(-KpB, dp, ep);
        buf[j & 3] = (ep - vsn - vsp) - cRO * vo;
        if ((j & 3) == 3) {
            const int t = t0 + j - 3;
            if (t + 4 <= T) {
                *reinterpret_cast<float4*>(orow + t) =
                    make_float4(buf[0], buf[1], buf[2], buf[3]);
            } else {
                #pragma unroll
                for (int m = 0; m < 4; ++m)
                    if (t + m < T) orow[t + m] = buf[m];
            }
        }
    }
}

// ============================================================================
// Serial fallback for T > 1024 — correctness insurance only.
// ============================================================================
__global__ __launch_bounds__(64) void battery_serial_kernel(
    const float* __restrict__ current, const float* __restrict__ init_state,
    const float* __restrict__ Ap_scale, const float* __restrict__ An0_scale,
    float* __restrict__ out, int B, int T)
{
    const int b = blockIdx.x * blockDim.x + threadIdx.x;
    if (b >= B) return;

    const float invF = (float)(1.0 / 96487.0);
    const float RO = 0.117215f, KN = 2120.96f, KP = 248898.0f;
    const float invQS = (float)(1.0 / (7600.0 / 0.6 * 0.1));
    const float iVB = (float)(1.0 / 126.0), iVS = (float)(1.0 / 14.0);
    const float invSN = (float)(1.0 / 0.000437545), invSP = (float)(1.0 / 0.00030962);
    const float invTO = (float)(1.0 / dTO), invTSN = (float)(1.0 / dTSN), invTSP = (float)(1.0 / dTSP);
    const float U0P = 4.03f, U0N = 0.01f;

    float Ap[13], Apk[13];
    #pragma unroll
    for (int k = 0; k < 13; ++k) { Ap[k] = Ap_scale[k] * kBaseAp[k]; Apk[k] = Ap[k] * (float)k; }
    const float An0 = An0_scale[0] * 86.19f;

    const float* st = init_state + (size_t)b * 8;
    float Tb = st[0], Vo = st[1], Vsn = st[2], Vsp = st[3];
    float qnB = st[4], qnS = st[5], qpB = st[6], qpS = st[7];
    const float coefVs = 8.3144621f * Tb * invF * 2.0f;
    const float coefL  = 8.3144621f * Tb * invF;

    const float* cur = current + (size_t)b * T;
    float* op = out + (size_t)b * T;

    for (int t = 0; t < T; ++t) {
        const float i = cur[t];
        float xnS = qnS * invQS, xpS = qpS * invQS;
        float Jn0 = KN * sqrtf(xnS * (1.0f - xnS));
        float Jp0 = KP * sqrtf(xpS * (1.0f - xpS));
        float dBSn = qnB * iVB - qnS * iVS;
        float dBSp = qpB * iVB - qpS * iVS;
        float zn = __fdividef(i * invSN, 2.0f * Jn0);
        float zp = __fdividef(i * invSP, 2.0f * Jp0);
        Vo  += (i * RO - Vo) * invTO;
        Vsn += (coefVs * fast_asinh(zn) - Vsn) * invTSN;
        Vsp += (coefVs * fast_asinh(zp) - Vsp) * invTSP;
        qnB -= dBSn; qnS += dBSn - i; qpB -= dBSp; qpS += i + dBSp;

        float xp = qpS * invQS, xn = qnS * invQS;
        float lp = __logf(__fdividef(1.0f - xp, xp));
        float ln = __logf(__fdividef(1.0f - xn, xn));
        float tp = 2.0f * xp - 1.0f, cp2 = 2.0f * xp * (1.0f - xp);
        float sum = Ap[0] * tp, pkm1 = 1.0f, pk = tp;
        #pragma unroll
        for (int k = 1; k < 13; ++k) {
            float pk1 = pk * tp;
            sum = __fmaf_rn(Ap[k], pk1, sum);
            sum = __fmaf_rn(-Apk[k] * cp2, pkm1, sum);
            pkm1 = pk; pk = pk1;
        }
        float tn = 2.0f * xn - 1.0f;
        op[t] = (U0P - U0N) + coefL * (lp - ln) + (sum - An0 * tn) * invF - Vo - Vsn - Vsp;
    }
}

extern "C" void kernel_launch(void* const* d_in, const int* in_sizes, int n_in,
                              void* d_out, int out_size, void* d_ws, size_t ws_size,
                              hipStream_t stream) {
    const float* current    = (const float*)d_in[0];
    const float* init_state = (const float*)d_in[1];
    const float* Ap_scale   = (const float*)d_in[2];
    const float* An0_scale  = (const float*)d_in[3];
    float* out = (float*)d_out;

    const int B = in_sizes[1] / 8;   // init_state is [B,8]
    const int T = in_sizes[0] / B;   // current is [B,T]

    if (T <= 1024) {
        // one 64-lane wave per batch element, 4 waves per 256-thread block
        dim3 block(256);
        dim3 grid((B + 3) / 4);
        hipLaunchKernelGGL(battery_scan_kernel, grid, block, 0, stream,
                           current, init_state, Ap_scale, An0_scale, out, B, T);
    } else {
        dim3 block(64);
        dim3 grid((B + 63) / 64);
        hipLaunchKernelGGL(battery_serial_kernel, grid, block, 0, stream,
                           current, init_state, Ap_scale, An0_scale, out, B, T);
    }
}

// Round 10
// 97.858 us; speedup vs baseline: 2.6810x; 1.2649x over previous
//
#include <hip/hip_runtime.h>
#include <math.h>

namespace {
__constant__ float kBaseAp[13] = {-31593.7f, 0.106747f, 24606.4f, -78561.9f, 13317.9f,
                                  307387.0f, 84916.1f, -1074690.0f, 2285.04f, 990894.0f,
                                  283920.0f, -161513.0f, -469218.0f};

constexpr double dTO  = 6.08671;
constexpr double dTSN = 1001.38;
constexpr double dTSP = 46.4311;
constexpr double dLAM = 58.0 / 63.0;          // 1 - (1/126 + 1/14)
constexpr double dAO  = 1.0 - 1.0 / dTO;
constexpr double dAN  = 1.0 - 1.0 / dTSN;
constexpr double dAP  = 1.0 - 1.0 / dTSP;

constexpr double cpow(double x, int n) {
    double r = 1.0;
    for (int i = 0; i < n; ++i) r *= x;
    return r;
}
}  // namespace

// force a (wave-uniform) float into an SGPR
__device__ __forceinline__ float rfl(float x) {
    union { float f; int i; } u;
    u.f = x;
    u.i = __builtin_amdgcn_readfirstlane(u.i);
    return u.f;
}

// asinh(z) = log(z + sqrt(z*z + 1)) — serial fallback only
__device__ __forceinline__ float fast_asinh(float z) {
    return __logf(z + sqrtf(__fmaf_rn(z, z, 1.0f)));
}

// ============================================================================
// Wave-parallel scan kernel: one 64-lane wave per batch element, 16 steps/lane.
// Valid for T <= 1024.
//
// Exact linear decomposition (R2-R9, verified passing):
//   QN'=QN-i (prefix sum); d'=lam*d +- i/14 (lam=58/63); x=(Q-+S)*cA - cB*d;
//   Vo,Vsn,Vsp geometric IIRs -> wave scans + per-lane replay.
// R5/R6: per-segment linearization at the 16-step anchor (error <~2e-4 V).
//
// R10: occupancy via NATURAL allocation, not forcing. Every forced bound
// (R7 (256,8), R9 (256,6)) made the allocator's pressure estimate (which
// overshoots ~30 regs on this kernel) spill cur[16] -> 80-120 MB scratch
// traffic, memory-bound at ~52 us. (256,4) = 128-reg ceiling: no spill;
// hardware resident-wave count follows the ACTUAL ~56-70 VGPR allocation
// (8 waves/SIMD at <=64).
//   * pass A eliminated by moment sums: vn = kn*(i + a1*g*i^3 + a2*g^2*i^5
//     + a3*g^3*i^7), g=gn2, so the an-weighted segment sum is
//     c_sn = kn*(M1 + g*(a1*M3 + g*(a2*M5 + g*a3*M7))), M_k accumulated in
//     phase 1 before the anchor is known (exact algebra).
//   * cur[16] loaded once; drives recomputed only in pass B
//   * grid-uniform RK coefficients in SGPRs (readfirstlane)
// ============================================================================
__global__ __launch_bounds__(256, 4) void battery_scan_kernel(
    const float* __restrict__ current,     // [B,T]
    const float* __restrict__ init_state,  // [B,8]
    const float* __restrict__ Ap_scale,    // [13]
    const float* __restrict__ An0_scale,   // [1]
    float* __restrict__ out,               // [B,T]
    int B, int T)
{
    constexpr int L = 16;                       // timesteps per lane
    const int lane = threadIdx.x & 63;
    const int wid  = threadIdx.x >> 6;
    const int b    = blockIdx.x * (blockDim.x >> 6) + wid;
    if (b >= B) return;                         // wave-uniform

    // ---- constants ----
    const float invF   = (float)(1.0 / 96487.0);
    const float invQS  = (float)(1.0 / (7600.0 / 0.6 * 0.1));
    const float inv14  = (float)(1.0 / 14.0);
    const float lam    = (float)dLAM;
    const float ao     = (float)dAO, an = (float)dAN, ap = (float)dAP;
    const float c1n = (float)(1.0 / (0.000437545 * 2.0 * 2120.96));
    const float c1p = (float)(1.0 / (0.00030962 * 2.0 * 248898.0));
    const float cA  = 0.1f * invQS;
    const float cB  = 12.6f * invQS;
    const float cRO    = (float)(0.117215 / dTO);
    const float invcRO = (float)(dTO / 0.117215);
    const float CC  = 4.03f - 0.01f;            // U0P - U0N
    // asinh(z)/z = 1 + z2*(a1 + z2*(a2 + z2*a3)), |z|<=0.56
    const float a1 = -1.0f / 6.0f, a2 = 3.0f / 40.0f, a3 = -15.0f / 336.0f;

    // scan level constants pole^(16*2^k), k=0..5 (compile-time literals)
    const float lamL[6] = {(float)cpow(dLAM,16),(float)cpow(dLAM,32),(float)cpow(dLAM,64),
                           (float)cpow(dLAM,128),(float)cpow(dLAM,256),(float)cpow(dLAM,512)};
    const float aoL[6]  = {(float)cpow(dAO,16),(float)cpow(dAO,32),(float)cpow(dAO,64),
                           (float)cpow(dAO,128),(float)cpow(dAO,256),(float)cpow(dAO,512)};
    const float anL[6]  = {(float)cpow(dAN,16),(float)cpow(dAN,32),(float)cpow(dAN,64),
                           (float)cpow(dAN,128),(float)cpow(dAN,256),(float)cpow(dAN,512)};
    const float apL[6]  = {(float)cpow(dAP,16),(float)cpow(dAP,32),(float)cpow(dAP,64),
                           (float)cpow(dAP,128),(float)cpow(dAP,256),(float)cpow(dAP,512)};

    // per-lane anchors pole^(16*lane): binary exponentiation over lane bits
    float lamt = 1.0f, aot = 1.0f, ant = 1.0f, apt = 1.0f;
    #pragma unroll
    for (int k = 0; k < 6; ++k) {
        if (lane & (1 << k)) {
            lamt *= lamL[k];
            aot  *= aoL[k];
            ant  *= anL[k];
            apt  *= apL[k];
        }
    }

    // ---- grid-uniform RK E/O Horner coefficients -> SGPRs (invF folded) ----
    float e0,e1,e2,e3,e4,e5,e6, o0,o1,o2,o3,o4,o5,o6, AnF;
    {
        float al[13], be[13];
        #pragma unroll
        for (int k = 0; k < 13; ++k) {
            const float A = Ap_scale[k] * kBaseAp[k] * invF;
            al[k] = A * (1.0f + 0.5f * (float)k);
            be[k] = -A * (0.5f * (float)k);
        }
        e0 = rfl(be[1]);
        e1 = rfl(al[1] + be[3]);
        e2 = rfl(al[3] + be[5]);
        e3 = rfl(al[5] + be[7]);
        e4 = rfl(al[7] + be[9]);
        e5 = rfl(al[9] + be[11]);
        e6 = rfl(al[11]);
        o0 = rfl((Ap_scale[0] * kBaseAp[0] * invF) + be[2]);
        o1 = rfl(al[2]  + be[4]);
        o2 = rfl(al[4]  + be[6]);
        o3 = rfl(al[6]  + be[8]);
        o4 = rfl(al[8]  + be[10]);
        o5 = rfl(al[10] + be[12]);
        o6 = rfl(al[12]);
        AnF = rfl(An0_scale[0] * 86.19f * invF);
    }

    // ---- per-element init state ----
    const float* st = init_state + (size_t)b * 8;
    const float Tb = st[0], Vo0 = st[1], Vsn0 = st[2], Vsp0 = st[3];
    const float qnB0 = st[4], qnS0 = st[5], qpB0 = st[6], qpS0 = st[7];
    const float QN0 = qnB0 + qnS0;
    const float QP0 = qpB0 + qpS0;
    const float dn0 = qnB0 * (float)(1.0/126.0) - qnS0 * inv14;
    const float dp0 = qpB0 * (float)(1.0/126.0) - qpS0 * inv14;
    const float coefVs = 8.3144621f * Tb * invF * 2.0f;
    const float coefL  = 8.3144621f * Tb * invF;
    const float cVn = coefVs * (float)(1.0 / dTSN);
    const float cVp = coefVs * (float)(1.0 / dTSP);

    // ---- load this lane's 16 currents ONCE (float4, tail-guarded) ----
    const float* row = current + (size_t)b * T;
    const int t0 = lane * L;
    float cur[L];
    #pragma unroll
    for (int k = 0; k < L / 4; ++k) {
        const int t = t0 + 4 * k;
        if (t + 4 <= T) {
            const float4 v = *reinterpret_cast<const float4*>(row + t);
            cur[4*k+0] = v.x; cur[4*k+1] = v.y; cur[4*k+2] = v.z; cur[4*k+3] = v.w;
        } else {
            #pragma unroll
            for (int m = 0; m < 4; ++m)
                cur[4*k+m] = (t + m < T) ? row[t + m] : 0.0f;
        }
    }

    // ---- phase 1: weighted local reductions, incl. moment sums M1,M3,M5,M7 ----
    float s_loc = 0.0f, cH = 0.0f, c_o = 0.0f, c_spr = 0.0f;
    float M1 = 0.0f, M3 = 0.0f, M5 = 0.0f, M7 = 0.0f;
    #pragma unroll
    for (int j = 0; j < L; ++j) {
        const float i = cur[j];
        s_loc += i;
        cH    = __fmaf_rn(lam, cH, i * inv14);
        c_o   = __fmaf_rn(ao, c_o, i);
        c_spr = __fmaf_rn(ap, c_spr, i);     // vp = kp*i -> kp folded in later
        const float i2 = i * i;
        const float i3 = i2 * i;
        const float i5 = i3 * i2;
        const float i7 = i5 * i2;
        M1 = __fmaf_rn(an, M1, i);
        M3 = __fmaf_rn(an, M3, i3);
        M5 = __fmaf_rn(an, M5, i5);
        M7 = __fmaf_rn(an, M7, i7);
    }

    // ---- phase 2: cumsum scan + C-only affine scan for h ----
    float s = s_loc;
    #pragma unroll
    for (int d = 1; d < 64; d <<= 1) {
        const float o = __shfl_up(s, (unsigned)d, 64);
        if (lane >= d) s += o;
    }
    const float Sx = s - s_loc;          // exclusive prefix sum at segment start

    float Ch = cH;
    #pragma unroll
    for (int k = 0; k < 6; ++k) {
        const int d = 1 << k;
        const float o = __shfl_up(Ch, (unsigned)d, 64);
        if (lane >= d) Ch = __fmaf_rn(lamL[k], o, Ch);
    }
    float h = __shfl_up(Ch, 1u, 64);
    if (lane == 0) h = 0.0f;

    // ---- anchor state at t0 ----
    float dn = __fmaf_rn(lamt, dn0, h);
    float dp = __fmaf_rn(lamt, dp0, -h);
    const float xn0 = (QN0 - Sx) * cA - dn * cB;
    const float xp0 = (QP0 + Sx) * cA - dp * cB;

    // ---- per-segment heavy eval (once per wave) ----
    float K0p, KnB, KpB, KdA, gn2, kn, kp;
    {
        const float pn0 = __fmaf_rn(-xn0, xn0, xn0);      // xn0*(1-xn0)
        const float pp0 = __fmaf_rn(-xp0, xp0, xp0);
        const float rn = __frsqrt_rn(pn0), rp = __frsqrt_rn(pp0);
        const float rn2 = rn * rn, rp2 = rp * rp;         // 1/(x(1-x))
        const float gn = c1n * rn;
        gn2 = gn * gn;
        kn  = cVn * gn;
        kp  = (cVp * c1p) * rp;
        const float fxn = __logf(__fdividef(1.0f - xn0, xn0));
        const float fxp = __logf(__fdividef(1.0f - xp0, xp0));

        const float tp0 = 2.0f * xp0 - 1.0f;
        const float u0  = tp0 * tp0;
        float E = __fmaf_rn(e6, u0, e5);
        E = __fmaf_rn(E, u0, e4); E = __fmaf_rn(E, u0, e3);
        E = __fmaf_rn(E, u0, e2); E = __fmaf_rn(E, u0, e1); E = __fmaf_rn(E, u0, e0);
        float O = __fmaf_rn(o6, u0, o5);
        O = __fmaf_rn(O, u0, o4); O = __fmaf_rn(O, u0, o3);
        O = __fmaf_rn(O, u0, o2); O = __fmaf_rn(O, u0, o1); O = __fmaf_rn(O, u0, o0);
        float Ep = __fmaf_rn(6.0f * e6, u0, 5.0f * e5);
        Ep = __fmaf_rn(Ep, u0, 4.0f * e4); Ep = __fmaf_rn(Ep, u0, 3.0f * e3);
        Ep = __fmaf_rn(Ep, u0, 2.0f * e2); Ep = __fmaf_rn(Ep, u0, e1);
        float Op = __fmaf_rn(6.0f * o6, u0, 5.0f * o5);
        Op = __fmaf_rn(Op, u0, 4.0f * o4); Op = __fmaf_rn(Op, u0, 3.0f * o3);
        Op = __fmaf_rn(Op, u0, 2.0f * o2); Op = __fmaf_rn(Op, u0, o1);
        const float rkf0 = __fmaf_rn(tp0, O, E);          // RK/F at anchor
        float Fp = __fmaf_rn(2.0f * tp0, Ep, O);          // dRK/dt = 2t E' + O + 2u O'
        Fp = __fmaf_rn(2.0f * u0, Op, Fp);

        const float tn0 = 2.0f * xn0 - 1.0f;
        const float K0 = CC + coefL * (fxp - fxn) + rkf0 - AnF * tn0;
        const float Kn = __fmaf_rn(coefL, rn2, -2.0f * AnF);   // -dVen/dxn
        const float Kp = __fmaf_rn(-coefL, rp2, 2.0f * Fp);    // dVep/dxp
        // ep_t = K0' - KnB*dn_t - KpB*dp_t + KdA*dS_t
        KnB = Kn * cB;
        KpB = Kp * cB;
        KdA = (Kp - Kn) * cA;
        K0p = K0 + KnB * dn + KpB * dp;   // dn,dp still hold anchor values here
    }

    // ---- c_sn from moment sums (exact expansion of the Taylor drive) ----
    const float c_sn = kn * __fmaf_rn(gn2,
                          __fmaf_rn(gn2, __fmaf_rn(gn2, a3 * M7, a2 * M5), a1 * M3),
                          M1);
    const float c_sp = kp * c_spr;

    // ---- phase 4: three C-only IIR scans ----
    float Co = c_o, Cn = c_sn, Cp = c_sp;
    #pragma unroll
    for (int k = 0; k < 6; ++k) {
        const int d = 1 << k;
        const float oo = __shfl_up(Co, (unsigned)d, 64);
        const float on = __shfl_up(Cn, (unsigned)d, 64);
        const float op = __shfl_up(Cp, (unsigned)d, 64);
        if (lane >= d) {
            Co = __fmaf_rn(aoL[k], oo, Co);
            Cn = __fmaf_rn(anL[k], on, Cn);
            Cp = __fmaf_rn(apL[k], op, Cp);
        }
    }
    float Cxo = __shfl_up(Co, 1u, 64);
    float Cxn = __shfl_up(Cn, 1u, 64);
    float Cxp = __shfl_up(Cp, 1u, 64);
    if (lane == 0) { Cxo = 0.0f; Cxn = 0.0f; Cxp = 0.0f; }
    float vo  = __fmaf_rn(aot, Vo0 * invcRO, Cxo);   // Vo/cRO at segment start
    float vsn = __fmaf_rn(ant, Vsn0, Cxn);
    float vsp = __fmaf_rn(apt, Vsp0, Cxp);

    // ---- pass B: replay — recompute drives, evolve dn/dp/dS, emit outputs ----
    float* orow = out + (size_t)b * T;
    float dS = 0.0f;
    float buf[4];
    #pragma unroll
    for (int j = 0; j < L; ++j) {
        const float i = cur[j];
        // drives (frozen-anchor Taylor form, same values as the moment sum)
        const float z2 = (i * i) * gn2;
        float Q = __fmaf_rn(a3, z2, a2);
        Q = __fmaf_rn(Q, z2, a1);
        const float vn = (i * kn) * __fmaf_rn(z2, Q, 1.0f);
        vo  = __fmaf_rn(ao, vo, i);
        vsn = __fmaf_rn(an, vsn, vn);
        vsp = __fmaf_rn(ap, vsp, i * kp);
        // linear state advance to t+1
        const float t14 = i * inv14;
        dn = __fmaf_rn(lam, dn, t14);
        dp = __fmaf_rn(lam, dp, -t14);
        dS += i;
        // linearized potential at t+1, minus IIR voltages
        float ep = __fmaf_rn(KdA, dS, K0p);
        ep = __fmaf_rn(-KnB, dn, ep);
        ep = __fmaf_rn(-KpB, dp, ep);
        buf[j & 3] = (ep - vsn - vsp) - cRO * vo;
        if ((j & 3) == 3) {
            const int t = t0 + j - 3;
            if (t + 4 <= T) {
                *reinterpret_cast<float4*>(orow + t) =
                    make_float4(buf[0], buf[1], buf[2], buf[3]);
            } else {
                #pragma unroll
                for (int m = 0; m < 4; ++m)
                    if (t + m < T) orow[t + m] = buf[m];
            }
        }
    }
}

// ============================================================================
// Serial fallback for T > 1024 — correctness insurance only.
// ============================================================================
__global__ __launch_bounds__(64) void battery_serial_kernel(
    const float* __restrict__ current, const float* __restrict__ init_state,
    const float* __restrict__ Ap_scale, const float* __restrict__ An0_scale,
    float* __restrict__ out, int B, int T)
{
    const int b = blockIdx.x * blockDim.x + threadIdx.x;
    if (b >= B) return;

    const float invF = (float)(1.0 / 96487.0);
    const float RO = 0.117215f, KN = 2120.96f, KP = 248898.0f;
    const float invQS = (float)(1.0 / (7600.0 / 0.6 * 0.1));
    const float iVB = (float)(1.0 / 126.0), iVS = (float)(1.0 / 14.0);
    const float invSN = (float)(1.0 / 0.000437545), invSP = (float)(1.0 / 0.00030962);
    const float invTO = (float)(1.0 / dTO), invTSN = (float)(1.0 / dTSN), invTSP = (float)(1.0 / dTSP);
    const float U0P = 4.03f, U0N = 0.01f;

    float Ap[13], Apk[13];
    #pragma unroll
    for (int k = 0; k < 13; ++k) { Ap[k] = Ap_scale[k] * kBaseAp[k]; Apk[k] = Ap[k] * (float)k; }
    const float An0 = An0_scale[0] * 86.19f;

    const float* st = init_state + (size_t)b * 8;
    float Tb = st[0], Vo = st[1], Vsn = st[2], Vsp = st[3];
    float qnB = st[4], qnS = st[5], qpB = st[6], qpS = st[7];
    const float coefVs = 8.3144621f * Tb * invF * 2.0f;
    const float coefL  = 8.3144621f * Tb * invF;

    const float* cur = current + (size_t)b * T;
    float* op = out + (size_t)b * T;

    for (int t = 0; t < T; ++t) {
        const float i = cur[t];
        float xnS = qnS * invQS, xpS = qpS * invQS;
        float Jn0 = KN * sqrtf(xnS * (1.0f - xnS));
        float Jp0 = KP * sqrtf(xpS * (1.0f - xpS));
        float dBSn = qnB * iVB - qnS * iVS;
        float dBSp = qpB * iVB - qpS * iVS;
        float zn = __fdividef(i * invSN, 2.0f * Jn0);
        float zp = __fdividef(i * invSP, 2.0f * Jp0);
        Vo  += (i * RO - Vo) * invTO;
        Vsn += (coefVs * fast_asinh(zn) - Vsn) * invTSN;
        Vsp += (coefVs * fast_asinh(zp) - Vsp) * invTSP;
        qnB -= dBSn; qnS += dBSn - i; qpB -= dBSp; qpS += i + dBSp;

        float xp = qpS * invQS, xn = qnS * invQS;
        float lp = __logf(__fdividef(1.0f - xp, xp));
        float ln = __logf(__fdividef(1.0f - xn, xn));
        float tp = 2.0f * xp - 1.0f, cp2 = 2.0f * xp * (1.0f - xp);
        float sum = Ap[0] * tp, pkm1 = 1.0f, pk = tp;
        #pragma unroll
        for (int k = 1; k < 13; ++k) {
            float pk1 = pk * tp;
            sum = __fmaf_rn(Ap[k], pk1, sum);
            sum = __fmaf_rn(-Apk[k] * cp2, pkm1, sum);
            pkm1 = pk; pk = pk1;
        }
        float tn = 2.0f * xn - 1.0f;
        op[t] = (U0P - U0N) + coefL * (lp - ln) + (sum - An0 * tn) * invF - Vo - Vsn - Vsp;
    }
}

extern "C" void kernel_launch(void* const* d_in, const int* in_sizes, int n_in,
                              void* d_out, int out_size, void* d_ws, size_t ws_size,
                              hipStream_t stream) {
    const float* current    = (const float*)d_in[0];
    const float* init_state = (const float*)d_in[1];
    const float* Ap_scale   = (const float*)d_in[2];
    const float* An0_scale  = (const float*)d_in[3];
    float* out = (float*)d_out;

    const int B = in_sizes[1] / 8;   // init_state is [B,8]
    const int T = in_sizes[0] / B;   // current is [B,T]

    if (T <= 1024) {
        // one 64-lane wave per batch element, 4 waves per 256-thread block
        dim3 block(256);
        dim3 grid((B + 3) / 4);
        hipLaunchKernelGGL(battery_scan_kernel, grid, block, 0, stream,
                           current, init_state, Ap_scale, An0_scale, out, B, T);
    } else {
        dim3 block(64);
        dim3 grid((B + 63) / 64);
        hipLaunchKernelGGL(battery_serial_kernel, grid, block, 0, stream,
                           current, init_state, Ap_scale, An0_scale, out, B, T);
    }
}